// Round 14
// baseline (450.769 us; speedup 1.0000x reference)
//
#include <hip/hip_runtime.h>
#include <hip/hip_bf16.h>

// MHA (8 heads, N=4096, D=512) + soft k-means (K=32). Round 26:
//  - attn: DOUBLE-BUFFERED K/V LDS (Ks[2]/Vt[2], +18KB -> ~63KB, still 2
//    blocks/CU). Step s stages tile s+1 into the idle buffer right after the
//    previous barrier, overlapped with QK^T/softmax/PV; ONE barrier per step
//    (was 2). Staged values identical -> bit-identical numerics.
//  - dkm: convergence bit ENCODED IN THE BARRIER GENERATION WORD. gen counts
//    by 2; master releaser of barrier #2 (all diffb adds provably visible at
//    its release) reads diffb[i] once and sets bit0 = (d > 1e-4). Pollers get
//    the decision in the word they already poll -> removes the ~900cy post-
//    barrier agent-load round for every block every iteration. Predicate and
//    asumb/Cn numerics untouched (R17 floor driver not touched).
//  - R24 tree barrier / R25 bf16-P / reg-prefetch / GEMMs otherwise identical.
// Output format (verified R9): d_out = 4-byte words, bf16 payload in HIGH 16 bits;
// words [0:16384] = C[32,512]; words [16384:147456] = a[4096,32].

typedef __hip_bfloat16 bf16;
typedef __attribute__((ext_vector_type(8))) short s16x8;
typedef __attribute__((ext_vector_type(4))) float f32x4;

__device__ __forceinline__ void  stv(float* p, float v) { *p = v; }
__device__ __forceinline__ void  stv(bf16*  p, float v) { *p = __float2bfloat16(v); }

// agent-scope (cross-XCD coherent) accesses for grid-shared data
__device__ __forceinline__ float gload(const float* p)
{
    return __hip_atomic_load(p, __ATOMIC_RELAXED, __HIP_MEMORY_SCOPE_AGENT);
}
__device__ __forceinline__ void gstore(float* p, float v)
{
    __hip_atomic_store(p, v, __ATOMIC_RELAXED, __HIP_MEMORY_SCOPE_AGENT);
}
__device__ __forceinline__ void gstore2(float2* p, float2 v)
{
    unsigned long long u; __builtin_memcpy(&u, &v, 8);
    __hip_atomic_store((unsigned long long*)p, u, __ATOMIC_RELAXED, __HIP_MEMORY_SCOPE_AGENT);
}

__device__ __forceinline__ unsigned bf16word(float v)
{
    bf16 b = __float2bfloat16(v);
    unsigned short u;
    __builtin_memcpy(&u, &b, 2);
    return ((unsigned)u) << 16;   // bf16 payload in HIGH 16 bits
}

__device__ __forceinline__ void stage8(const float* g, bf16* d)
{
    const float4 a = *(const float4*)g;
    const float4 b = *(const float4*)(g + 4);
    union { uint4 u; bf16 h[8]; } r;
    r.h[0] = __float2bfloat16(a.x); r.h[1] = __float2bfloat16(a.y);
    r.h[2] = __float2bfloat16(a.z); r.h[3] = __float2bfloat16(a.w);
    r.h[4] = __float2bfloat16(b.x); r.h[5] = __float2bfloat16(b.y);
    r.h[6] = __float2bfloat16(b.z); r.h[7] = __float2bfloat16(b.w);
    *(uint4*)d = r.u;
}
__device__ __forceinline__ void stage8(const bf16* g, bf16* d)
{
    *(uint4*)d = *(const uint4*)g;
}
__device__ __forceinline__ void load8f(const float* g, float* v)
{
    const float4 a = *(const float4*)g; const float4 b = *(const float4*)(g + 4);
    v[0]=a.x; v[1]=a.y; v[2]=a.z; v[3]=a.w; v[4]=b.x; v[5]=b.y; v[6]=b.z; v[7]=b.w;
}
__device__ __forceinline__ void load8f(const bf16* g, float* v)
{
    union { uint4 u; bf16 h[8]; } r; r.u = *(const uint4*)g;
#pragma unroll
    for (int j = 0; j < 8; j++) v[j] = __bfloat162float(r.h[j]);
}

struct P3 { const void* a[3]; const void* b[3]; const float* bi[3]; void* c[3]; };

template<typename TA, typename TB, typename TC, bool BT, bool BIAS>
__global__ __launch_bounds__(256) void mgemm(P3 p, int M, int N, int K)
{
    __shared__ __align__(16) bf16 As[64][40];
    __shared__ __align__(16) bf16 Bs[64][40];
    const int z = blockIdx.z;
    const TA* A = (const TA*)p.a[z];
    const TB* B = (const TB*)p.b[z];
    const float* bias = p.bi[z];
    TC* C = (TC*)p.c[z];
    const int m0 = blockIdx.x * 64, n0 = blockIdx.y * 64;
    const int t = threadIdx.x;
    const int w = t >> 6, lane = t & 63, quad = lane >> 4, l15 = lane & 15;
    f32x4 acc[4];
#pragma unroll
    for (int i = 0; i < 4; i++) acc[i] = (f32x4){0.f, 0.f, 0.f, 0.f};
    for (int k0 = 0; k0 < K; k0 += 32) {
        {
            int r = t >> 2, c = (t & 3) * 8;
            stage8(&A[(size_t)(m0 + r) * K + k0 + c], &As[r][c]);
        }
        if constexpr (BT) {
            int r = t >> 2, c = (t & 3) * 8;
            stage8(&B[(size_t)(n0 + r) * K + k0 + c], &Bs[r][c]);
        } else {
            int k = t >> 3, n8 = (t & 7) * 8;
            float v[8];
            load8f(&B[(size_t)(k0 + k) * N + n0 + n8], v);
#pragma unroll
            for (int j = 0; j < 8; j++) Bs[n8 + j][k] = __float2bfloat16(v[j]);
        }
        __syncthreads();
        s16x8 af = *(const s16x8*)&As[w * 16 + l15][quad * 8];
#pragma unroll
        for (int nt = 0; nt < 4; nt++) {
            s16x8 bfv = *(const s16x8*)&Bs[nt * 16 + l15][quad * 8];
            acc[nt] = __builtin_amdgcn_mfma_f32_16x16x32_bf16(af, bfv, acc[nt], 0, 0, 0);
        }
        __syncthreads();
    }
#pragma unroll
    for (int nt = 0; nt < 4; nt++) {
        int col = n0 + nt * 16 + l15;
        float bv = 0.f;
        if constexpr (BIAS) bv = bias[col];
#pragma unroll
        for (int r = 0; r < 4; r++) {
            int row = m0 + w * 16 + quad * 4 + r;
            stv(&C[(size_t)row * N + col], acc[nt][r] + bv);
        }
    }
}

// attn: R25 core + R26 double-buffered K/V (one barrier per kb-step).
__global__ __launch_bounds__(256) void attn_mfma(
    const bf16* __restrict__ qh, const bf16* __restrict__ kh,
    const bf16* __restrict__ vh, bf16* __restrict__ oatt)
{
    __shared__ __align__(16) bf16  Qs[64][72];
    __shared__ __align__(16) bf16  Ks[2][64][72];
    __shared__ __align__(16) bf16  Vt[2][64][72]; // chunk-XOR swizzled cols
    __shared__ __align__(16) float Ss[64][68];    // raw scaled scores
    __shared__ __align__(16) bf16  Ps[64][72];    // P in bf16 (softmax output)
    __shared__ float mrow[64], lrow[64], arow[64];
    const int bid = blockIdx.x;
    const int h = bid & 7, q0 = (bid >> 3) * 64;
    const int t = threadIdx.x;
    const int w = t >> 6, lane = t & 63, quad = lane >> 4, l15 = lane & 15;

#pragma unroll
    for (int i = 0; i < 2; i++) {
        int idx = t + i * 256;
        int r = idx >> 3, c = (idx & 7) * 8;
        *(uint4*)&Qs[r][c] = *(const uint4*)&qh[(size_t)(q0 + r) * 512 + h * 64 + c];
    }
    if (t < 64) { mrow[t] = -1e30f; lrow[t] = 0.f; }
    f32x4 accO[4];
#pragma unroll
    for (int i = 0; i < 4; i++) accO[i] = (f32x4){0.f, 0.f, 0.f, 0.f};

    const int sidx0 = t, sidx1 = t + 256;
    const int sr0 = sidx0 >> 3, sc0 = (sidx0 & 7) * 8;
    const int sr1 = sidx1 >> 3, sc1v = (sidx1 & 7) * 8;
    // prologue: tile 0 -> regs -> buf0; tile 1 -> regs; single barrier
    uint4 kreg0 = *(const uint4*)&kh[(size_t)sr0 * 512 + h * 64 + sc0];
    uint4 vreg0 = *(const uint4*)&vh[(size_t)sr0 * 512 + h * 64 + sc0];
    uint4 kreg1 = *(const uint4*)&kh[(size_t)sr1 * 512 + h * 64 + sc1v];
    uint4 vreg1 = *(const uint4*)&vh[(size_t)sr1 * 512 + h * 64 + sc1v];
    {
        *(uint4*)&Ks[0][sr0][sc0] = kreg0;
        union { uint4 u; bf16 b[8]; } vv; vv.u = vreg0;
        int rlo = sr0 & 7, rch = sr0 >> 3, rx = sidx0 & 7;
#pragma unroll
        for (int j = 0; j < 8; j++)
            Vt[0][sc0 + j][rlo | (((rch ^ rx) & 7) << 3)] = vv.b[j];
    }
    {
        *(uint4*)&Ks[0][sr1][sc1v] = kreg1;
        union { uint4 u; bf16 b[8]; } vv; vv.u = vreg1;
        int rlo = sr1 & 7, rch = sr1 >> 3, rx = sidx1 & 7;
#pragma unroll
        for (int j = 0; j < 8; j++)
            Vt[0][sc1v + j][rlo | (((rch ^ rx) & 7) << 3)] = vv.b[j];
    }
    {
        size_t base0 = (size_t)(64 + sr0) * 512 + h * 64;
        size_t base1 = (size_t)(64 + sr1) * 512 + h * 64;
        kreg0 = *(const uint4*)&kh[base0 + sc0];
        vreg0 = *(const uint4*)&vh[base0 + sc0];
        kreg1 = *(const uint4*)&kh[base1 + sc1v];
        vreg1 = *(const uint4*)&vh[base1 + sc1v];
    }
    __syncthreads();

    for (int s = 0; s < 64; s++) {
        const int cur = s & 1;
        if (s + 1 < 64) {   // stage tile s+1 into the idle buffer (overlaps compute)
            const int nxt = cur ^ 1;
            {
                *(uint4*)&Ks[nxt][sr0][sc0] = kreg0;
                union { uint4 u; bf16 b[8]; } vv; vv.u = vreg0;
                int rlo = sr0 & 7, rch = sr0 >> 3, rx = sidx0 & 7;
#pragma unroll
                for (int j = 0; j < 8; j++)
                    Vt[nxt][sc0 + j][rlo | (((rch ^ rx) & 7) << 3)] = vv.b[j];
            }
            {
                *(uint4*)&Ks[nxt][sr1][sc1v] = kreg1;
                union { uint4 u; bf16 b[8]; } vv; vv.u = vreg1;
                int rlo = sr1 & 7, rch = sr1 >> 3, rx = sidx1 & 7;
#pragma unroll
                for (int j = 0; j < 8; j++)
                    Vt[nxt][sc1v + j][rlo | (((rch ^ rx) & 7) << 3)] = vv.b[j];
            }
            if (s + 2 < 64) {   // issue tile s+2 loads; latency hides under compute
                size_t base0 = (size_t)((s + 2) * 64 + sr0) * 512 + h * 64;
                size_t base1 = (size_t)((s + 2) * 64 + sr1) * 512 + h * 64;
                kreg0 = *(const uint4*)&kh[base0 + sc0];
                vreg0 = *(const uint4*)&vh[base0 + sc0];
                kreg1 = *(const uint4*)&kh[base1 + sc1v];
                vreg1 = *(const uint4*)&vh[base1 + sc1v];
            }
        }
        f32x4 accS[4];
#pragma unroll
        for (int i = 0; i < 4; i++) accS[i] = (f32x4){0.f, 0.f, 0.f, 0.f};
        __builtin_amdgcn_s_setprio(1);
#pragma unroll
        for (int dc = 0; dc < 64; dc += 32) {
            s16x8 aq = *(const s16x8*)&Qs[w * 16 + l15][dc + quad * 8];
#pragma unroll
            for (int nt = 0; nt < 4; nt++) {
                s16x8 bk = *(const s16x8*)&Ks[cur][nt * 16 + l15][dc + quad * 8];
                accS[nt] = __builtin_amdgcn_mfma_f32_16x16x32_bf16(aq, bk, accS[nt], 0, 0, 0);
            }
        }
        __builtin_amdgcn_s_setprio(0);
        // Ss/Ps rows [16w,16w+16) are WAVE-PRIVATE through PV: no barriers.
#pragma unroll
        for (int nt = 0; nt < 4; nt++)
#pragma unroll
            for (int r = 0; r < 4; r++)
                Ss[w * 16 + quad * 4 + r][nt * 16 + l15] = accS[nt][r] * 0.1803368801f;
        {   // wave-parallel online softmax: 4 threads per row, 16 cols each
            const int srow = t >> 2, sseg = t & 3;
            float* sp = &Ss[srow][sseg * 16];
            float4 s0 = *(const float4*)(sp + 0);
            float4 s1 = *(const float4*)(sp + 4);
            float4 s2 = *(const float4*)(sp + 8);
            float4 s3 = *(const float4*)(sp + 12);
            float mold = mrow[srow];
            float m01 = fmaxf(fmaxf(s0.x, s0.y), fmaxf(s0.z, s0.w));
            float m23 = fmaxf(fmaxf(s1.x, s1.y), fmaxf(s1.z, s1.w));
            float m45 = fmaxf(fmaxf(s2.x, s2.y), fmaxf(s2.z, s2.w));
            float m67 = fmaxf(fmaxf(s3.x, s3.y), fmaxf(s3.z, s3.w));
            float mx = fmaxf(fmaxf(m01, m23), fmaxf(m45, m67));
            mx = fmaxf(mx, mold);
            mx = fmaxf(mx, __shfl_xor(mx, 1));
            mx = fmaxf(mx, __shfl_xor(mx, 2));
            s0.x = exp2f(s0.x - mx); s0.y = exp2f(s0.y - mx);
            s0.z = exp2f(s0.z - mx); s0.w = exp2f(s0.w - mx);
            s1.x = exp2f(s1.x - mx); s1.y = exp2f(s1.y - mx);
            s1.z = exp2f(s1.z - mx); s1.w = exp2f(s1.w - mx);
            s2.x = exp2f(s2.x - mx); s2.y = exp2f(s2.y - mx);
            s2.z = exp2f(s2.z - mx); s2.w = exp2f(s2.w - mx);
            s3.x = exp2f(s3.x - mx); s3.y = exp2f(s3.y - mx);
            s3.z = exp2f(s3.z - mx); s3.w = exp2f(s3.w - mx);
            union { uint4 u; bf16 h[8]; } pa, pb;
            pa.h[0] = __float2bfloat16(s0.x); pa.h[1] = __float2bfloat16(s0.y);
            pa.h[2] = __float2bfloat16(s0.z); pa.h[3] = __float2bfloat16(s0.w);
            pa.h[4] = __float2bfloat16(s1.x); pa.h[5] = __float2bfloat16(s1.y);
            pa.h[6] = __float2bfloat16(s1.z); pa.h[7] = __float2bfloat16(s1.w);
            pb.h[0] = __float2bfloat16(s2.x); pb.h[1] = __float2bfloat16(s2.y);
            pb.h[2] = __float2bfloat16(s2.z); pb.h[3] = __float2bfloat16(s2.w);
            pb.h[4] = __float2bfloat16(s3.x); pb.h[5] = __float2bfloat16(s3.y);
            pb.h[6] = __float2bfloat16(s3.z); pb.h[7] = __float2bfloat16(s3.w);
            *(uint4*)&Ps[srow][sseg * 16]     = pa.u;
            *(uint4*)&Ps[srow][sseg * 16 + 8] = pb.u;
            float ps = (s0.x + s0.y + s0.z + s0.w) + (s1.x + s1.y + s1.z + s1.w)
                     + (s2.x + s2.y + s2.z + s2.w) + (s3.x + s3.y + s3.z + s3.w);
            ps += __shfl_xor(ps, 1);
            ps += __shfl_xor(ps, 2);
            if (sseg == 0) {
                float al = exp2f(mold - mx);
                lrow[srow] = lrow[srow] * al + ps;
                mrow[srow] = mx;
                arow[srow] = al;
            }
        }
        float al4[4];
#pragma unroll
        for (int r = 0; r < 4; r++) al4[r] = arow[w * 16 + quad * 4 + r];
#pragma unroll
        for (int dt = 0; dt < 4; dt++)
#pragma unroll
            for (int r = 0; r < 4; r++) accO[dt][r] *= al4[r];
        __builtin_amdgcn_s_setprio(1);
#pragma unroll
        for (int kc = 0; kc < 64; kc += 32) {
            s16x8 pf = *(const s16x8*)&Ps[w * 16 + l15][kc + quad * 8];
#pragma unroll
            for (int dt = 0; dt < 4; dt++) {
                int vrow = dt * 16 + l15;
                s16x8 bv = *(const s16x8*)&Vt[cur][vrow][((((kc >> 3) + quad) ^ (vrow >> 3)) & 7) << 3];
                accO[dt] = __builtin_amdgcn_mfma_f32_16x16x32_bf16(pf, bv, accO[dt], 0, 0, 0);
            }
        }
        __builtin_amdgcn_s_setprio(0);
        __syncthreads();   // single barrier: protects next step's staging + reads
    }
#pragma unroll
    for (int dt = 0; dt < 4; dt++)
#pragma unroll
        for (int r = 0; r < 4; r++) {
            int row = w * 16 + quad * 4 + r;
            oatt[(size_t)(q0 + row) * 512 + h * 64 + dt * 16 + l15] =
                __float2bfloat16(accO[dt][r] / lrow[row]);
        }
}

__global__ __launch_bounds__(64) void k_bar_init(unsigned* bar, unsigned* gen)
{
    if (threadIdx.x < 9) bar[threadIdx.x] = 0u;
    if (threadIdx.x == 0) *gen = 0u;
}

// tree grid barrier (R24) with R26 gen-encoded flag: gen advances by
// generation = gen>>1; bit0 carries the releaser's predicate (d > thr).
// Returns bit0 of the new gen word (0 for flagless barriers).
__device__ __forceinline__ unsigned gridbar_f(unsigned* bar, unsigned* gen,
                                              const float* dptr, float thr,
                                              unsigned* bcast)
{
    __syncthreads();
    if (threadIdx.x == 0) {
        unsigned g = __hip_atomic_load(gen, __ATOMIC_RELAXED, __HIP_MEMORY_SCOPE_AGENT);
        const int sub = blockIdx.x & 7;
        unsigned newg = 0;
        bool released = false;
        if (__hip_atomic_fetch_add(&bar[sub], 1u, __ATOMIC_RELAXED, __HIP_MEMORY_SCOPE_AGENT) == 15u) {
            __hip_atomic_store(&bar[sub], 0u, __ATOMIC_RELAXED, __HIP_MEMORY_SCOPE_AGENT);
            asm volatile("s_waitcnt vmcnt(0)" ::: "memory");
            if (__hip_atomic_fetch_add(&bar[8], 1u, __ATOMIC_RELAXED, __HIP_MEMORY_SCOPE_AGENT) == 7u) {
                __hip_atomic_store(&bar[8], 0u, __ATOMIC_RELAXED, __HIP_MEMORY_SCOPE_AGENT);
                unsigned flag = 0u;
                if (dptr) flag = (gload(dptr) > thr) ? 1u : 0u;
                asm volatile("s_waitcnt vmcnt(0)" ::: "memory");
                newg = (((g >> 1) + 1u) << 1) | flag;
                __hip_atomic_store(gen, newg, __ATOMIC_RELAXED, __HIP_MEMORY_SCOPE_AGENT);
                released = true;
            }
        }
        if (!released) {
            unsigned ng;
            do {
                ng = __hip_atomic_load(gen, __ATOMIC_RELAXED, __HIP_MEMORY_SCOPE_AGENT);
                if ((ng >> 1) != (g >> 1)) break;
                __builtin_amdgcn_s_sleep(1);
            } while (true);
            newg = ng;
        }
        *bcast = newg;
    }
    __syncthreads();
    return *bcast & 1u;
}

// persistent DKM: R24 structure + R26 gen-encoded convergence decision.
__global__ __launch_bounds__(256) void dkm_persist(
    const float* __restrict__ X, const int* __restrict__ idxp,
    float* __restrict__ Cacc, float* __restrict__ Cb0, float* __restrict__ Cb1,
    float* __restrict__ asumb, float* __restrict__ diffb, float* __restrict__ cnormb,
    unsigned* bar, unsigned* gen, unsigned* __restrict__ out)
{
    const int b = blockIdx.x, t = threadIdx.x;
    const int n0 = b * 32;
    __shared__ float Cs[128][32];
    __shared__ float as_[32][32];
    __shared__ float red[256];
    __shared__ float xn[32];
    __shared__ unsigned gw;

    // phase 0: xnorm (LDS-persistent), gather C0, zero per-iteration slots
    {
        int rl = t >> 3, j = t & 7;
        const float* p = X + (size_t)(n0 + rl) * 512 + j * 64;
        float s = 0.f;
#pragma unroll
        for (int i = 0; i < 64; i++) { float v = p[i]; s += v * v; }
        as_[rl][j] = s;
        __syncthreads();
        if (t < 32) {
            float tot = 0.f;
#pragma unroll
            for (int jj = 0; jj < 8; jj++) tot += as_[t][jj];
            xn[t] = tot;
        }
        if (t < 128) {
            int o = b * 128 + t;             // o = e*32+k
            gstore(&Cb0[o], X[(size_t)idxp[o & 31] * 512 + (o >> 5)]);
        }
        int z = b * 256 + t;
        if (z < 3072) gstore(&asumb[z], 0.f);   // tail holds bar counters
        if (z < 97)   gstore(&diffb[z], 0.f);
        if (z < 3136) gstore(&cnormb[z], 0.f);
    }
    gridbar_f(bar, gen, nullptr, 0.f, &gw);
    if (b < 32) {   // cnorm of C0
        float s = 0.f;
        for (int e = t; e < 512; e += 256) { float v = gload(&Cb0[e * 32 + b]); s += v * v; }
        red[t] = s; __syncthreads();
        for (int st = 128; st > 0; st >>= 1) { if (t < st) red[t] += red[t + st]; __syncthreads(); }
        if (t == 0) gstore(&cnormb[b], red[0]);
    }
    gridbar_f(bar, gen, nullptr, 0.f, &gw);

    const int k = t & 31, rg = t >> 5;
    int ifin = 96;
    float pre[16];
#pragma unroll
    for (int j = 0; j < 16; j++) pre[j] = gload(&Cb0[t + j * 256]);   // chunk 0 of C0
    for (int i = 0; i <= 96; i++) {
        const float* Cc = (i & 1) ? Cb1 : Cb0;
        float* Cn = (i & 1) ? Cb0 : Cb1;
        // ---- assign: chunked staging with register prefetch (T14) ----
        float dots[4] = {0.f, 0.f, 0.f, 0.f};
        for (int ec = 0; ec < 4; ec++) {
            __syncthreads();
#pragma unroll
            for (int j = 0; j < 16; j++) {
                int idx = t + j * 256;
                Cs[idx >> 5][idx & 31] = pre[j];
            }
            __syncthreads();
            if (ec < 3) {   // prefetch next chunk under this chunk's compute
#pragma unroll
                for (int j = 0; j < 16; j++)
                    pre[j] = gload(&Cc[(ec + 1) * 4096 + t + j * 256]);
            }
            const float* xb = X + (size_t)(n0 + rg) * 512 + ec * 128;
#pragma unroll 4
            for (int ee4 = 0; ee4 < 128; ee4 += 4) {
                float4 x0 = *(const float4*)&xb[ee4];
                float4 x1 = *(const float4*)&xb[8 * 512 + ee4];
                float4 x2 = *(const float4*)&xb[16 * 512 + ee4];
                float4 x3 = *(const float4*)&xb[24 * 512 + ee4];
                {
                    float cv = Cs[ee4 + 0][k];
                    dots[0] += x0.x * cv; dots[1] += x1.x * cv;
                    dots[2] += x2.x * cv; dots[3] += x3.x * cv;
                }
                {
                    float cv = Cs[ee4 + 1][k];
                    dots[0] += x0.y * cv; dots[1] += x1.y * cv;
                    dots[2] += x2.y * cv; dots[3] += x3.y * cv;
                }
                {
                    float cv = Cs[ee4 + 2][k];
                    dots[0] += x0.z * cv; dots[1] += x1.z * cv;
                    dots[2] += x2.z * cv; dots[3] += x3.z * cv;
                }
                {
                    float cv = Cs[ee4 + 3][k];
                    dots[0] += x0.w * cv; dots[1] += x1.w * cv;
                    dots[2] += x2.w * cv; dots[3] += x3.w * cv;
                }
            }
        }
        float cn = gload(&cnormb[i * 32 + k]);
#pragma unroll
        for (int rr = 0; rr < 4; rr++) {
            int rl = rg + rr * 8;
            float d2 = xn[rl] + cn - 2.f * dots[rr];
            as_[rl][k] = -2.f * sqrtf(fmaxf(d2, 0.f));   // -d/TEMP, TEMP=0.5
        }
        __syncthreads();
        if (t < 32) {   // softmax per row
            float mx = -1e30f;
            for (int kk = 0; kk < 32; kk++) mx = fmaxf(mx, as_[t][kk]);
            float su = 0.f;
            for (int kk = 0; kk < 32; kk++) su += expf(as_[t][kk] - mx);
            float inv = 1.f / su;
            for (int kk = 0; kk < 32; kk++) as_[t][kk] = expf(as_[t][kk] - mx) * inv;
        }
        __syncthreads();
        if (i == 96) {                     // cap: keep Cc, a(Cc); single a-write
#pragma unroll
            for (int i2 = 0; i2 < 4; i2++) {
                int o = t + i2 * 256;
                int r = o >> 5, kk = o & 31;
                out[16384 + (n0 + r) * 32 + kk] = bf16word(as_[r][kk]);
            }
            break;
        }
        if (t < 32) {
            float s = 0.f;
            for (int r = 0; r < 32; r++) s += as_[r][t];
            atomicAdd(&asumb[i * 32 + t], s);
        }
        {   // local a^T X partials
            float acc[64];
#pragma unroll
            for (int i2 = 0; i2 < 64; i2++) acc[i2] = 0.f;
            const float2* X2 = (const float2*)(X + (size_t)n0 * 512);
            for (int r = 0; r < 32; r++) {
                float2 xv = X2[r * 256 + t];
                const float4* ar4 = (const float4*)as_[r];
#pragma unroll
                for (int kq = 0; kq < 8; kq++) {
                    float4 av = ar4[kq];
                    acc[(kq * 4 + 0) * 2 + 0] += av.x * xv.x; acc[(kq * 4 + 0) * 2 + 1] += av.x * xv.y;
                    acc[(kq * 4 + 1) * 2 + 0] += av.y * xv.x; acc[(kq * 4 + 1) * 2 + 1] += av.y * xv.y;
                    acc[(kq * 4 + 2) * 2 + 0] += av.z * xv.x; acc[(kq * 4 + 2) * 2 + 1] += av.z * xv.y;
                    acc[(kq * 4 + 3) * 2 + 0] += av.w * xv.x; acc[(kq * 4 + 3) * 2 + 1] += av.w * xv.y;
                }
            }
            float2* cb = (float2*)(Cacc + (size_t)b * 16384);
#pragma unroll
            for (int k2 = 0; k2 < 32; k2++) {
                float2 wv; wv.x = acc[k2 * 2 + 0]; wv.y = acc[k2 * 2 + 1];
                gstore2(&cb[k2 * 256 + t], wv);
            }
        }
        gridbar_f(bar, gen, nullptr, 0.f, &gw);
        // ---- reduce: Cn, diffb[i], cnormb[i+1] ----
        {
            const int j = t & 127, half = t >> 7;
            const int o = b * 128 + j;       // o = k*512+e ; block covers kk = b>>2
            float s = 0.f;
            for (int p = half * 64; p < half * 64 + 64; p++) s += gload(&Cacc[(size_t)p * 16384 + o]);
            red[t] = s;
            __syncthreads();
            float df = 0.f, cp = 0.f;
            if (t < 128) {
                float tot = red[t] + red[t + 128];
                int kk = o >> 9, e = o & 511;
                float cn2 = tot / (gload(&asumb[i * 32 + kk]) + 1e-6f);
                gstore(&Cn[e * 32 + kk], cn2);
                df = fabsf(cn2 - gload(&Cc[e * 32 + kk]));
                cp = cn2 * cn2;
            }
            __syncthreads();
            red[t] = df; __syncthreads();
            for (int st = 128; st > 0; st >>= 1) { if (t < st) red[t] += red[t + st]; __syncthreads(); }
            if (t == 0) atomicAdd(&diffb[i], red[0]);
            __syncthreads();
            red[t] = cp; __syncthreads();
            for (int st = 128; st > 0; st >>= 1) { if (t < st) red[t] += red[t + st]; __syncthreads(); }
            if (t == 0) atomicAdd(&cnormb[(i + 1) * 32 + (b >> 2)], red[0]);
        }
        // barrier #2 carries the convergence decision in gen bit0
        unsigned cont = gridbar_f(bar, gen, &diffb[i], 1e-4f, &gw);
        if (!cont) {   // converged: keep Cc, a; single a-write
            ifin = i;
#pragma unroll
            for (int i2 = 0; i2 < 4; i2++) {
                int o = t + i2 * 256;
                int r = o >> 5, kk = o & 31;
                out[16384 + (n0 + r) * 32 + kk] = bf16word(as_[r][kk]);
            }
            break;
        }
        // prefetch chunk 0 of the NEXT iteration's C (Cn just finalized)
#pragma unroll
        for (int j = 0; j < 16; j++) pre[j] = gload(&Cn[t + j * 256]);
    }
    // final C -> out
    {
        const float* Cf = (ifin & 1) ? Cb1 : Cb0;
        if (t < 128) {
            int idx = b * 128 + t;          // idx = kk*512 + e
            int kk = idx >> 9, e = idx & 511;
            out[idx] = bf16word(gload(&Cf[e * 32 + kk]));
        }
    }
}

extern "C" void kernel_launch(void* const* d_in, const int* in_sizes, int n_in,
                              void* d_out, int out_size, void* d_ws, size_t ws_size,
                              hipStream_t stream)
{
    const size_t NEED = 25323292;
    if (ws_size < NEED) return;

    const float* emb = (const float*)d_in[0];
    const float* qw  = (const float*)d_in[1];
    const float* kw  = (const float*)d_in[2];
    const float* vw  = (const float*)d_in[3];
    const float* ipw = (const float*)d_in[4];
    const float* ipb = (const float*)d_in[5];
    const float* ow  = (const float*)d_in[6];
    const float* ob  = (const float*)d_in[7];
    const int*   idx = (const int*)d_in[8];
    unsigned* out = (unsigned*)d_out;

    float* ws    = (float*)d_ws;
    bf16*  qkv   = (bf16*)ws;               // [3][4096][512] bf16  (0..3145728 fp-slots)
    bf16*  weff  = (bf16*)(ws + 3145728);   // [3][768][512] bf16
    bf16*  oatt  = (bf16*)(ws + 3145728);   // alias weff (dead after qkv gemm)
    float* X     = ws;                      // alias qkv (dead after attn)
    float* Cacc  = ws + 4194304;            // 2,097,152 floats (128 partials)
    float* Cb0   = ws + 6291456;            // 16384
    float* Cb1   = ws + 6307840;            // 16384
    float* asumb = ws + 6324224;            // 96*32 used; tail holds bar counters
    float* diffb = ws + 6327456;            // 97 used
    float* cnormb= ws + 6327557;            // 97*32 used
    unsigned* bar = (unsigned*)(ws + 6324224 + 3072);   // 9 counters in asumb tail
    unsigned* gen = (unsigned*)(ws + 6330822);

    bf16* qh = qkv;
    bf16* kh = qkv + 2097152;
    bf16* vh = qkv + 4194304;

    k_bar_init<<<1, 64, 0, stream>>>(bar, gen);

    // weff_z = zw @ Wz^T
    P3 pw;
    pw.a[0] = qw;  pw.a[1] = kw;  pw.a[2] = vw;
    pw.b[0] = ipw; pw.b[1] = ipw + 262144; pw.b[2] = ipw + 524288;
    pw.bi[0] = pw.bi[1] = pw.bi[2] = nullptr;
    pw.c[0] = weff; pw.c[1] = weff + 393216; pw.c[2] = weff + 786432;
    mgemm<float, float, bf16, true, false><<<dim3(12, 8, 3), 256, 0, stream>>>(pw, 768, 512, 512);

    // qkv_z = emb @ weff_z + bias_z
    P3 pq;
    pq.a[0] = pq.a[1] = pq.a[2] = emb;
    pq.b[0] = weff; pq.b[1] = weff + 393216; pq.b[2] = weff + 786432;
    pq.bi[0] = ipb; pq.bi[1] = ipb + 512; pq.bi[2] = ipb + 1024;
    pq.c[0] = qh; pq.c[1] = kh; pq.c[2] = vh;
    mgemm<float, bf16, bf16, false, true><<<dim3(64, 8, 3), 256, 0, stream>>>(pq, 4096, 512, 768);

    attn_mfma<<<dim3(512), 256, 0, stream>>>(qh, kh, vh, oatt);

    // X = oatt @ out_w^T + out_b
    P3 pt;
    pt.a[0] = oatt; pt.b[0] = ow; pt.bi[0] = ob; pt.c[0] = X;
    pt.a[1] = pt.a[2] = pt.b[1] = pt.b[2] = nullptr;
    pt.bi[1] = pt.bi[2] = nullptr; pt.c[1] = pt.c[2] = nullptr;
    mgemm<bf16, float, float, true, true><<<dim3(64, 8, 1), 256, 0, stream>>>(pt, 4096, 512, 512);

    dkm_persist<<<dim3(128), 256, 0, stream>>>(X, idx, Cacc, Cb0, Cb1,
                                               asumb, diffb, cnormb, bar, gen, out);
}

// Round 15
// 440.916 us; speedup vs baseline: 1.0223x; 1.0223x over previous
//
#include <hip/hip_runtime.h>
#include <hip/hip_bf16.h>

// MHA (8 heads, N=4096, D=512) + soft k-means (K=32). Round 27:
//  - dkm: 512 THREADS/BLOCK (was 256). R26 arithmetic: 2 waves/CU on 128 CUs,
//    ~10k serial VALU cycles/iter = 3.5us/iter => VALU-issue-bound. 512 threads
//    halve per-thread FMA in the two big phases:
//      * assign: 16 row-groups x 2 rows (dots[2]); each dot still summed
//        ee-ascending -> bit-identical as_ values.
//      * aTX: thread-halves split k in [0,16)/[16,32); each Cacc element still
//        accumulated r-ascending by ONE thread -> bit-identical partials.
//    Reduce/diffb/asumb/softmax/xnorm/cnorm keep the EXACT 256-thread layout
//    (threads >=256 idle; barriers hoisted, block-uniform) -> diffb trajectory
//    and absmax bit-identical (R17 lesson).
//  - attn (R26 double-buffer) / GEMMs / tree barrier + gen-flag unchanged.
// Output format (verified R9): d_out = 4-byte words, bf16 payload in HIGH 16 bits;
// words [0:16384] = C[32,512]; words [16384:147456] = a[4096,32].

typedef __hip_bfloat16 bf16;
typedef __attribute__((ext_vector_type(8))) short s16x8;
typedef __attribute__((ext_vector_type(4))) float f32x4;

__device__ __forceinline__ void  stv(float* p, float v) { *p = v; }
__device__ __forceinline__ void  stv(bf16*  p, float v) { *p = __float2bfloat16(v); }

// agent-scope (cross-XCD coherent) accesses for grid-shared data
__device__ __forceinline__ float gload(const float* p)
{
    return __hip_atomic_load(p, __ATOMIC_RELAXED, __HIP_MEMORY_SCOPE_AGENT);
}
__device__ __forceinline__ void gstore(float* p, float v)
{
    __hip_atomic_store(p, v, __ATOMIC_RELAXED, __HIP_MEMORY_SCOPE_AGENT);
}
__device__ __forceinline__ void gstore2(float2* p, float2 v)
{
    unsigned long long u; __builtin_memcpy(&u, &v, 8);
    __hip_atomic_store((unsigned long long*)p, u, __ATOMIC_RELAXED, __HIP_MEMORY_SCOPE_AGENT);
}

__device__ __forceinline__ unsigned bf16word(float v)
{
    bf16 b = __float2bfloat16(v);
    unsigned short u;
    __builtin_memcpy(&u, &b, 2);
    return ((unsigned)u) << 16;   // bf16 payload in HIGH 16 bits
}

__device__ __forceinline__ void stage8(const float* g, bf16* d)
{
    const float4 a = *(const float4*)g;
    const float4 b = *(const float4*)(g + 4);
    union { uint4 u; bf16 h[8]; } r;
    r.h[0] = __float2bfloat16(a.x); r.h[1] = __float2bfloat16(a.y);
    r.h[2] = __float2bfloat16(a.z); r.h[3] = __float2bfloat16(a.w);
    r.h[4] = __float2bfloat16(b.x); r.h[5] = __float2bfloat16(b.y);
    r.h[6] = __float2bfloat16(b.z); r.h[7] = __float2bfloat16(b.w);
    *(uint4*)d = r.u;
}
__device__ __forceinline__ void stage8(const bf16* g, bf16* d)
{
    *(uint4*)d = *(const uint4*)g;
}
__device__ __forceinline__ void load8f(const float* g, float* v)
{
    const float4 a = *(const float4*)g; const float4 b = *(const float4*)(g + 4);
    v[0]=a.x; v[1]=a.y; v[2]=a.z; v[3]=a.w; v[4]=b.x; v[5]=b.y; v[6]=b.z; v[7]=b.w;
}
__device__ __forceinline__ void load8f(const bf16* g, float* v)
{
    union { uint4 u; bf16 h[8]; } r; r.u = *(const uint4*)g;
#pragma unroll
    for (int j = 0; j < 8; j++) v[j] = __bfloat162float(r.h[j]);
}

struct P3 { const void* a[3]; const void* b[3]; const float* bi[3]; void* c[3]; };

template<typename TA, typename TB, typename TC, bool BT, bool BIAS>
__global__ __launch_bounds__(256) void mgemm(P3 p, int M, int N, int K)
{
    __shared__ __align__(16) bf16 As[64][40];
    __shared__ __align__(16) bf16 Bs[64][40];
    const int z = blockIdx.z;
    const TA* A = (const TA*)p.a[z];
    const TB* B = (const TB*)p.b[z];
    const float* bias = p.bi[z];
    TC* C = (TC*)p.c[z];
    const int m0 = blockIdx.x * 64, n0 = blockIdx.y * 64;
    const int t = threadIdx.x;
    const int w = t >> 6, lane = t & 63, quad = lane >> 4, l15 = lane & 15;
    f32x4 acc[4];
#pragma unroll
    for (int i = 0; i < 4; i++) acc[i] = (f32x4){0.f, 0.f, 0.f, 0.f};
    for (int k0 = 0; k0 < K; k0 += 32) {
        {
            int r = t >> 2, c = (t & 3) * 8;
            stage8(&A[(size_t)(m0 + r) * K + k0 + c], &As[r][c]);
        }
        if constexpr (BT) {
            int r = t >> 2, c = (t & 3) * 8;
            stage8(&B[(size_t)(n0 + r) * K + k0 + c], &Bs[r][c]);
        } else {
            int k = t >> 3, n8 = (t & 7) * 8;
            float v[8];
            load8f(&B[(size_t)(k0 + k) * N + n0 + n8], v);
#pragma unroll
            for (int j = 0; j < 8; j++) Bs[n8 + j][k] = __float2bfloat16(v[j]);
        }
        __syncthreads();
        s16x8 af = *(const s16x8*)&As[w * 16 + l15][quad * 8];
#pragma unroll
        for (int nt = 0; nt < 4; nt++) {
            s16x8 bfv = *(const s16x8*)&Bs[nt * 16 + l15][quad * 8];
            acc[nt] = __builtin_amdgcn_mfma_f32_16x16x32_bf16(af, bfv, acc[nt], 0, 0, 0);
        }
        __syncthreads();
    }
#pragma unroll
    for (int nt = 0; nt < 4; nt++) {
        int col = n0 + nt * 16 + l15;
        float bv = 0.f;
        if constexpr (BIAS) bv = bias[col];
#pragma unroll
        for (int r = 0; r < 4; r++) {
            int row = m0 + w * 16 + quad * 4 + r;
            stv(&C[(size_t)row * N + col], acc[nt][r] + bv);
        }
    }
}

// attn: R25 core + R26 double-buffered K/V (one barrier per kb-step).
__global__ __launch_bounds__(256) void attn_mfma(
    const bf16* __restrict__ qh, const bf16* __restrict__ kh,
    const bf16* __restrict__ vh, bf16* __restrict__ oatt)
{
    __shared__ __align__(16) bf16  Qs[64][72];
    __shared__ __align__(16) bf16  Ks[2][64][72];
    __shared__ __align__(16) bf16  Vt[2][64][72]; // chunk-XOR swizzled cols
    __shared__ __align__(16) float Ss[64][68];    // raw scaled scores
    __shared__ __align__(16) bf16  Ps[64][72];    // P in bf16 (softmax output)
    __shared__ float mrow[64], lrow[64], arow[64];
    const int bid = blockIdx.x;
    const int h = bid & 7, q0 = (bid >> 3) * 64;
    const int t = threadIdx.x;
    const int w = t >> 6, lane = t & 63, quad = lane >> 4, l15 = lane & 15;

#pragma unroll
    for (int i = 0; i < 2; i++) {
        int idx = t + i * 256;
        int r = idx >> 3, c = (idx & 7) * 8;
        *(uint4*)&Qs[r][c] = *(const uint4*)&qh[(size_t)(q0 + r) * 512 + h * 64 + c];
    }
    if (t < 64) { mrow[t] = -1e30f; lrow[t] = 0.f; }
    f32x4 accO[4];
#pragma unroll
    for (int i = 0; i < 4; i++) accO[i] = (f32x4){0.f, 0.f, 0.f, 0.f};

    const int sidx0 = t, sidx1 = t + 256;
    const int sr0 = sidx0 >> 3, sc0 = (sidx0 & 7) * 8;
    const int sr1 = sidx1 >> 3, sc1v = (sidx1 & 7) * 8;
    // prologue: tile 0 -> regs -> buf0; tile 1 -> regs; single barrier
    uint4 kreg0 = *(const uint4*)&kh[(size_t)sr0 * 512 + h * 64 + sc0];
    uint4 vreg0 = *(const uint4*)&vh[(size_t)sr0 * 512 + h * 64 + sc0];
    uint4 kreg1 = *(const uint4*)&kh[(size_t)sr1 * 512 + h * 64 + sc1v];
    uint4 vreg1 = *(const uint4*)&vh[(size_t)sr1 * 512 + h * 64 + sc1v];
    {
        *(uint4*)&Ks[0][sr0][sc0] = kreg0;
        union { uint4 u; bf16 b[8]; } vv; vv.u = vreg0;
        int rlo = sr0 & 7, rch = sr0 >> 3, rx = sidx0 & 7;
#pragma unroll
        for (int j = 0; j < 8; j++)
            Vt[0][sc0 + j][rlo | (((rch ^ rx) & 7) << 3)] = vv.b[j];
    }
    {
        *(uint4*)&Ks[0][sr1][sc1v] = kreg1;
        union { uint4 u; bf16 b[8]; } vv; vv.u = vreg1;
        int rlo = sr1 & 7, rch = sr1 >> 3, rx = sidx1 & 7;
#pragma unroll
        for (int j = 0; j < 8; j++)
            Vt[0][sc1v + j][rlo | (((rch ^ rx) & 7) << 3)] = vv.b[j];
    }
    {
        size_t base0 = (size_t)(64 + sr0) * 512 + h * 64;
        size_t base1 = (size_t)(64 + sr1) * 512 + h * 64;
        kreg0 = *(const uint4*)&kh[base0 + sc0];
        vreg0 = *(const uint4*)&vh[base0 + sc0];
        kreg1 = *(const uint4*)&kh[base1 + sc1v];
        vreg1 = *(const uint4*)&vh[base1 + sc1v];
    }
    __syncthreads();

    for (int s = 0; s < 64; s++) {
        const int cur = s & 1;
        if (s + 1 < 64) {   // stage tile s+1 into the idle buffer (overlaps compute)
            const int nxt = cur ^ 1;
            {
                *(uint4*)&Ks[nxt][sr0][sc0] = kreg0;
                union { uint4 u; bf16 b[8]; } vv; vv.u = vreg0;
                int rlo = sr0 & 7, rch = sr0 >> 3, rx = sidx0 & 7;
#pragma unroll
                for (int j = 0; j < 8; j++)
                    Vt[nxt][sc0 + j][rlo | (((rch ^ rx) & 7) << 3)] = vv.b[j];
            }
            {
                *(uint4*)&Ks[nxt][sr1][sc1v] = kreg1;
                union { uint4 u; bf16 b[8]; } vv; vv.u = vreg1;
                int rlo = sr1 & 7, rch = sr1 >> 3, rx = sidx1 & 7;
#pragma unroll
                for (int j = 0; j < 8; j++)
                    Vt[nxt][sc1v + j][rlo | (((rch ^ rx) & 7) << 3)] = vv.b[j];
            }
            if (s + 2 < 64) {   // issue tile s+2 loads; latency hides under compute
                size_t base0 = (size_t)((s + 2) * 64 + sr0) * 512 + h * 64;
                size_t base1 = (size_t)((s + 2) * 64 + sr1) * 512 + h * 64;
                kreg0 = *(const uint4*)&kh[base0 + sc0];
                vreg0 = *(const uint4*)&vh[base0 + sc0];
                kreg1 = *(const uint4*)&kh[base1 + sc1v];
                vreg1 = *(const uint4*)&vh[base1 + sc1v];
            }
        }
        f32x4 accS[4];
#pragma unroll
        for (int i = 0; i < 4; i++) accS[i] = (f32x4){0.f, 0.f, 0.f, 0.f};
        __builtin_amdgcn_s_setprio(1);
#pragma unroll
        for (int dc = 0; dc < 64; dc += 32) {
            s16x8 aq = *(const s16x8*)&Qs[w * 16 + l15][dc + quad * 8];
#pragma unroll
            for (int nt = 0; nt < 4; nt++) {
                s16x8 bk = *(const s16x8*)&Ks[cur][nt * 16 + l15][dc + quad * 8];
                accS[nt] = __builtin_amdgcn_mfma_f32_16x16x32_bf16(aq, bk, accS[nt], 0, 0, 0);
            }
        }
        __builtin_amdgcn_s_setprio(0);
        // Ss/Ps rows [16w,16w+16) are WAVE-PRIVATE through PV: no barriers.
#pragma unroll
        for (int nt = 0; nt < 4; nt++)
#pragma unroll
            for (int r = 0; r < 4; r++)
                Ss[w * 16 + quad * 4 + r][nt * 16 + l15] = accS[nt][r] * 0.1803368801f;
        {   // wave-parallel online softmax: 4 threads per row, 16 cols each
            const int srow = t >> 2, sseg = t & 3;
            float* sp = &Ss[srow][sseg * 16];
            float4 s0 = *(const float4*)(sp + 0);
            float4 s1 = *(const float4*)(sp + 4);
            float4 s2 = *(const float4*)(sp + 8);
            float4 s3 = *(const float4*)(sp + 12);
            float mold = mrow[srow];
            float m01 = fmaxf(fmaxf(s0.x, s0.y), fmaxf(s0.z, s0.w));
            float m23 = fmaxf(fmaxf(s1.x, s1.y), fmaxf(s1.z, s1.w));
            float m45 = fmaxf(fmaxf(s2.x, s2.y), fmaxf(s2.z, s2.w));
            float m67 = fmaxf(fmaxf(s3.x, s3.y), fmaxf(s3.z, s3.w));
            float mx = fmaxf(fmaxf(m01, m23), fmaxf(m45, m67));
            mx = fmaxf(mx, mold);
            mx = fmaxf(mx, __shfl_xor(mx, 1));
            mx = fmaxf(mx, __shfl_xor(mx, 2));
            s0.x = exp2f(s0.x - mx); s0.y = exp2f(s0.y - mx);
            s0.z = exp2f(s0.z - mx); s0.w = exp2f(s0.w - mx);
            s1.x = exp2f(s1.x - mx); s1.y = exp2f(s1.y - mx);
            s1.z = exp2f(s1.z - mx); s1.w = exp2f(s1.w - mx);
            s2.x = exp2f(s2.x - mx); s2.y = exp2f(s2.y - mx);
            s2.z = exp2f(s2.z - mx); s2.w = exp2f(s2.w - mx);
            s3.x = exp2f(s3.x - mx); s3.y = exp2f(s3.y - mx);
            s3.z = exp2f(s3.z - mx); s3.w = exp2f(s3.w - mx);
            union { uint4 u; bf16 h[8]; } pa, pb;
            pa.h[0] = __float2bfloat16(s0.x); pa.h[1] = __float2bfloat16(s0.y);
            pa.h[2] = __float2bfloat16(s0.z); pa.h[3] = __float2bfloat16(s0.w);
            pa.h[4] = __float2bfloat16(s1.x); pa.h[5] = __float2bfloat16(s1.y);
            pa.h[6] = __float2bfloat16(s1.z); pa.h[7] = __float2bfloat16(s1.w);
            pb.h[0] = __float2bfloat16(s2.x); pb.h[1] = __float2bfloat16(s2.y);
            pb.h[2] = __float2bfloat16(s2.z); pb.h[3] = __float2bfloat16(s2.w);
            pb.h[4] = __float2bfloat16(s3.x); pb.h[5] = __float2bfloat16(s3.y);
            pb.h[6] = __float2bfloat16(s3.z); pb.h[7] = __float2bfloat16(s3.w);
            *(uint4*)&Ps[srow][sseg * 16]     = pa.u;
            *(uint4*)&Ps[srow][sseg * 16 + 8] = pb.u;
            float ps = (s0.x + s0.y + s0.z + s0.w) + (s1.x + s1.y + s1.z + s1.w)
                     + (s2.x + s2.y + s2.z + s2.w) + (s3.x + s3.y + s3.z + s3.w);
            ps += __shfl_xor(ps, 1);
            ps += __shfl_xor(ps, 2);
            if (sseg == 0) {
                float al = exp2f(mold - mx);
                lrow[srow] = lrow[srow] * al + ps;
                mrow[srow] = mx;
                arow[srow] = al;
            }
        }
        float al4[4];
#pragma unroll
        for (int r = 0; r < 4; r++) al4[r] = arow[w * 16 + quad * 4 + r];
#pragma unroll
        for (int dt = 0; dt < 4; dt++)
#pragma unroll
            for (int r = 0; r < 4; r++) accO[dt][r] *= al4[r];
        __builtin_amdgcn_s_setprio(1);
#pragma unroll
        for (int kc = 0; kc < 64; kc += 32) {
            s16x8 pf = *(const s16x8*)&Ps[w * 16 + l15][kc + quad * 8];
#pragma unroll
            for (int dt = 0; dt < 4; dt++) {
                int vrow = dt * 16 + l15;
                s16x8 bv = *(const s16x8*)&Vt[cur][vrow][((((kc >> 3) + quad) ^ (vrow >> 3)) & 7) << 3];
                accO[dt] = __builtin_amdgcn_mfma_f32_16x16x32_bf16(pf, bv, accO[dt], 0, 0, 0);
            }
        }
        __builtin_amdgcn_s_setprio(0);
        __syncthreads();   // single barrier: protects next step's staging + reads
    }
#pragma unroll
    for (int dt = 0; dt < 4; dt++)
#pragma unroll
        for (int r = 0; r < 4; r++) {
            int row = w * 16 + quad * 4 + r;
            oatt[(size_t)(q0 + row) * 512 + h * 64 + dt * 16 + l15] =
                __float2bfloat16(accO[dt][r] / lrow[row]);
        }
}

__global__ __launch_bounds__(64) void k_bar_init(unsigned* bar, unsigned* gen)
{
    if (threadIdx.x < 9) bar[threadIdx.x] = 0u;
    if (threadIdx.x == 0) *gen = 0u;
}

// tree grid barrier (R24) with gen-encoded flag (R26).
__device__ __forceinline__ unsigned gridbar_f(unsigned* bar, unsigned* gen,
                                              const float* dptr, float thr,
                                              unsigned* bcast)
{
    __syncthreads();
    if (threadIdx.x == 0) {
        unsigned g = __hip_atomic_load(gen, __ATOMIC_RELAXED, __HIP_MEMORY_SCOPE_AGENT);
        const int sub = blockIdx.x & 7;
        unsigned newg = 0;
        bool released = false;
        if (__hip_atomic_fetch_add(&bar[sub], 1u, __ATOMIC_RELAXED, __HIP_MEMORY_SCOPE_AGENT) == 15u) {
            __hip_atomic_store(&bar[sub], 0u, __ATOMIC_RELAXED, __HIP_MEMORY_SCOPE_AGENT);
            asm volatile("s_waitcnt vmcnt(0)" ::: "memory");
            if (__hip_atomic_fetch_add(&bar[8], 1u, __ATOMIC_RELAXED, __HIP_MEMORY_SCOPE_AGENT) == 7u) {
                __hip_atomic_store(&bar[8], 0u, __ATOMIC_RELAXED, __HIP_MEMORY_SCOPE_AGENT);
                unsigned flag = 0u;
                if (dptr) flag = (gload(dptr) > thr) ? 1u : 0u;
                asm volatile("s_waitcnt vmcnt(0)" ::: "memory");
                newg = (((g >> 1) + 1u) << 1) | flag;
                __hip_atomic_store(gen, newg, __ATOMIC_RELAXED, __HIP_MEMORY_SCOPE_AGENT);
                released = true;
            }
        }
        if (!released) {
            unsigned ng;
            do {
                ng = __hip_atomic_load(gen, __ATOMIC_RELAXED, __HIP_MEMORY_SCOPE_AGENT);
                if ((ng >> 1) != (g >> 1)) break;
                __builtin_amdgcn_s_sleep(1);
            } while (true);
            newg = ng;
        }
        *bcast = newg;
    }
    __syncthreads();
    return *bcast & 1u;
}

// persistent DKM: 128 blocks x 512 THREADS. Assign (16 grp x 2 rows) and aTX
// (k-halves) use all 512 threads with bit-identical per-element summation
// order; reduce/softmax/asumb/xnorm/cnorm keep the exact 256-thread layout.
__global__ __launch_bounds__(512) void dkm_persist(
    const float* __restrict__ X, const int* __restrict__ idxp,
    float* __restrict__ Cacc, float* __restrict__ Cb0, float* __restrict__ Cb1,
    float* __restrict__ asumb, float* __restrict__ diffb, float* __restrict__ cnormb,
    unsigned* bar, unsigned* gen, unsigned* __restrict__ out)
{
    const int b = blockIdx.x, t = threadIdx.x;
    const int n0 = b * 32;
    __shared__ float Cs[128][32];
    __shared__ float as_[32][32];
    __shared__ float red[256];
    __shared__ float xn[32];
    __shared__ unsigned gw;

    // phase 0 (original 256-thread layout; barriers hoisted)
    if (t < 256) {
        int rl = t >> 3, j = t & 7;
        const float* p = X + (size_t)(n0 + rl) * 512 + j * 64;
        float s = 0.f;
#pragma unroll
        for (int i = 0; i < 64; i++) { float v = p[i]; s += v * v; }
        as_[rl][j] = s;
    }
    __syncthreads();
    if (t < 32) {
        float tot = 0.f;
#pragma unroll
        for (int jj = 0; jj < 8; jj++) tot += as_[t][jj];
        xn[t] = tot;
    }
    if (t < 128) {
        int o = b * 128 + t;             // o = e*32+k
        gstore(&Cb0[o], X[(size_t)idxp[o & 31] * 512 + (o >> 5)]);
    }
    if (t < 256) {
        int z = b * 256 + t;
        if (z < 3072) gstore(&asumb[z], 0.f);   // tail holds bar counters
        if (z < 97)   gstore(&diffb[z], 0.f);
        if (z < 3136) gstore(&cnormb[z], 0.f);
    }
    gridbar_f(bar, gen, nullptr, 0.f, &gw);
    if (b < 32) {   // cnorm of C0 (256-thread layout; barriers block-uniform)
        if (t < 256) {
            float s = 0.f;
            for (int e = t; e < 512; e += 256) { float v = gload(&Cb0[e * 32 + b]); s += v * v; }
            red[t] = s;
        }
        __syncthreads();
        for (int st = 128; st > 0; st >>= 1) { if (t < st) red[t] += red[t + st]; __syncthreads(); }
        if (t == 0) gstore(&cnormb[b], red[0]);
    }
    gridbar_f(bar, gen, nullptr, 0.f, &gw);

    const int k = t & 31, rg = t >> 5;       // rg in [0,16): rows rg, rg+16
    const int col = t & 255, kgrp = t >> 8;  // aTX: k-half [kgrp*16, kgrp*16+16)
    int ifin = 96;
    float pre[8];
#pragma unroll
    for (int j = 0; j < 8; j++) pre[j] = gload(&Cb0[t + j * 512]);   // chunk 0 of C0
    for (int i = 0; i <= 96; i++) {
        const float* Cc = (i & 1) ? Cb1 : Cb0;
        float* Cn = (i & 1) ? Cb0 : Cb1;
        // ---- assign: chunked staging with register prefetch ----
        float dots[2] = {0.f, 0.f};
        for (int ec = 0; ec < 4; ec++) {
            __syncthreads();
#pragma unroll
            for (int j = 0; j < 8; j++) {
                int idx = t + j * 512;
                Cs[idx >> 5][idx & 31] = pre[j];
            }
            __syncthreads();
            if (ec < 3) {   // prefetch next chunk under this chunk's compute
#pragma unroll
                for (int j = 0; j < 8; j++)
                    pre[j] = gload(&Cc[(ec + 1) * 4096 + t + j * 512]);
            }
            const float* xb = X + (size_t)(n0 + rg) * 512 + ec * 128;
            // rows rg (dots[0]) and rg+16 (dots[1]); ee ascending -> bit-identical
#pragma unroll 4
            for (int ee4 = 0; ee4 < 128; ee4 += 4) {
                float4 x0 = *(const float4*)&xb[ee4];
                float4 x1 = *(const float4*)&xb[16 * 512 + ee4];
                {
                    float cv = Cs[ee4 + 0][k];
                    dots[0] += x0.x * cv; dots[1] += x1.x * cv;
                }
                {
                    float cv = Cs[ee4 + 1][k];
                    dots[0] += x0.y * cv; dots[1] += x1.y * cv;
                }
                {
                    float cv = Cs[ee4 + 2][k];
                    dots[0] += x0.z * cv; dots[1] += x1.z * cv;
                }
                {
                    float cv = Cs[ee4 + 3][k];
                    dots[0] += x0.w * cv; dots[1] += x1.w * cv;
                }
            }
        }
        float cn = gload(&cnormb[i * 32 + k]);
#pragma unroll
        for (int rr = 0; rr < 2; rr++) {
            int rl = rg + rr * 16;
            float d2 = xn[rl] + cn - 2.f * dots[rr];
            as_[rl][k] = -2.f * sqrtf(fmaxf(d2, 0.f));   // -d/TEMP, TEMP=0.5
        }
        __syncthreads();
        if (t < 32) {   // softmax per row (unchanged layout)
            float mx = -1e30f;
            for (int kk = 0; kk < 32; kk++) mx = fmaxf(mx, as_[t][kk]);
            float su = 0.f;
            for (int kk = 0; kk < 32; kk++) su += expf(as_[t][kk] - mx);
            float inv = 1.f / su;
            for (int kk = 0; kk < 32; kk++) as_[t][kk] = expf(as_[t][kk] - mx) * inv;
        }
        __syncthreads();
        if (i == 96) {                     // cap: keep Cc, a(Cc); single a-write
#pragma unroll
            for (int i2 = 0; i2 < 2; i2++) {
                int o = t + i2 * 512;
                int r = o >> 5, kk = o & 31;
                out[16384 + (n0 + r) * 32 + kk] = bf16word(as_[r][kk]);
            }
            break;
        }
        if (t < 32) {
            float s = 0.f;
            for (int r = 0; r < 32; r++) s += as_[r][t];
            atomicAdd(&asumb[i * 32 + t], s);
        }
        {   // local a^T X partials: k-half per thread-group, r ascending
            float acc[32];
#pragma unroll
            for (int i2 = 0; i2 < 32; i2++) acc[i2] = 0.f;
            const float2* X2 = (const float2*)(X + (size_t)n0 * 512);
            const float4* arb = (const float4*)&as_[0][kgrp * 16];
            for (int r = 0; r < 32; r++) {
                float2 xv = X2[r * 256 + col];
                const float4* ar4 = (const float4*)&as_[r][kgrp * 16];
#pragma unroll
                for (int kq = 0; kq < 4; kq++) {
                    float4 av = ar4[kq];
                    acc[(kq * 4 + 0) * 2 + 0] += av.x * xv.x; acc[(kq * 4 + 0) * 2 + 1] += av.x * xv.y;
                    acc[(kq * 4 + 1) * 2 + 0] += av.y * xv.x; acc[(kq * 4 + 1) * 2 + 1] += av.y * xv.y;
                    acc[(kq * 4 + 2) * 2 + 0] += av.z * xv.x; acc[(kq * 4 + 2) * 2 + 1] += av.z * xv.y;
                    acc[(kq * 4 + 3) * 2 + 0] += av.w * xv.x; acc[(kq * 4 + 3) * 2 + 1] += av.w * xv.y;
                }
            }
            (void)arb;
            float2* cb = (float2*)(Cacc + (size_t)b * 16384);
#pragma unroll
            for (int kq2 = 0; kq2 < 16; kq2++) {
                int k2 = kgrp * 16 + kq2;
                float2 wv; wv.x = acc[kq2 * 2 + 0]; wv.y = acc[kq2 * 2 + 1];
                gstore2(&cb[k2 * 256 + col], wv);
            }
        }
        gridbar_f(bar, gen, nullptr, 0.f, &gw);
        // ---- reduce: Cn, diffb[i], cnormb[i+1] (EXACT 256-thread layout) ----
        {
            float s = 0.f;
            if (t < 256) {
                const int j = t & 127, half = t >> 7;
                const int o = b * 128 + j;
                for (int p = half * 64; p < half * 64 + 64; p++) s += gload(&Cacc[(size_t)p * 16384 + o]);
                red[t] = s;
            }
            __syncthreads();
            float df = 0.f, cp = 0.f;
            if (t < 128) {
                const int o = b * 128 + (t & 127);
                float tot = red[t] + red[t + 128];
                int kk = o >> 9, e = o & 511;
                float cn2 = tot / (gload(&asumb[i * 32 + kk]) + 1e-6f);
                gstore(&Cn[e * 32 + kk], cn2);
                df = fabsf(cn2 - gload(&Cc[e * 32 + kk]));
                cp = cn2 * cn2;
            }
            __syncthreads();
            if (t < 256) red[t] = (t < 128) ? df : 0.f;
            __syncthreads();
            for (int st = 128; st > 0; st >>= 1) { if (t < st) red[t] += red[t + st]; __syncthreads(); }
            if (t == 0) atomicAdd(&diffb[i], red[0]);
            __syncthreads();
            if (t < 256) red[t] = (t < 128) ? cp : 0.f;
            __syncthreads();
            for (int st = 128; st > 0; st >>= 1) { if (t < st) red[t] += red[t + st]; __syncthreads(); }
            if (t == 0) atomicAdd(&cnormb[(i + 1) * 32 + (b >> 2)], red[0]);
        }
        // barrier #2 carries the convergence decision in gen bit0
        unsigned cont = gridbar_f(bar, gen, &diffb[i], 1e-4f, &gw);
        if (!cont) {   // converged: keep Cc, a; single a-write
            ifin = i;
#pragma unroll
            for (int i2 = 0; i2 < 2; i2++) {
                int o = t + i2 * 512;
                int r = o >> 5, kk = o & 31;
                out[16384 + (n0 + r) * 32 + kk] = bf16word(as_[r][kk]);
            }
            break;
        }
        // prefetch chunk 0 of the NEXT iteration's C (Cn just finalized)
#pragma unroll
        for (int j = 0; j < 8; j++) pre[j] = gload(&Cn[t + j * 512]);
    }
    // final C -> out
    {
        const float* Cf = (ifin & 1) ? Cb1 : Cb0;
        if (t < 128) {
            int idx = b * 128 + t;          // idx = kk*512 + e
            int kk = idx >> 9, e = idx & 511;
            out[idx] = bf16word(gload(&Cf[e * 32 + kk]));
        }
    }
}

extern "C" void kernel_launch(void* const* d_in, const int* in_sizes, int n_in,
                              void* d_out, int out_size, void* d_ws, size_t ws_size,
                              hipStream_t stream)
{
    const size_t NEED = 25323292;
    if (ws_size < NEED) return;

    const float* emb = (const float*)d_in[0];
    const float* qw  = (const float*)d_in[1];
    const float* kw  = (const float*)d_in[2];
    const float* vw  = (const float*)d_in[3];
    const float* ipw = (const float*)d_in[4];
    const float* ipb = (const float*)d_in[5];
    const float* ow  = (const float*)d_in[6];
    const float* ob  = (const float*)d_in[7];
    const int*   idx = (const int*)d_in[8];
    unsigned* out = (unsigned*)d_out;

    float* ws    = (float*)d_ws;
    bf16*  qkv   = (bf16*)ws;               // [3][4096][512] bf16  (0..3145728 fp-slots)
    bf16*  weff  = (bf16*)(ws + 3145728);   // [3][768][512] bf16
    bf16*  oatt  = (bf16*)(ws + 3145728);   // alias weff (dead after qkv gemm)
    float* X     = ws;                      // alias qkv (dead after attn)
    float* Cacc  = ws + 4194304;            // 2,097,152 floats (128 partials)
    float* Cb0   = ws + 6291456;            // 16384
    float* Cb1   = ws + 6307840;            // 16384
    float* asumb = ws + 6324224;            // 96*32 used; tail holds bar counters
    float* diffb = ws + 6327456;            // 97 used
    float* cnormb= ws + 6327557;            // 97*32 used
    unsigned* bar = (unsigned*)(ws + 6324224 + 3072);   // 9 counters in asumb tail
    unsigned* gen = (unsigned*)(ws + 6330822);

    bf16* qh = qkv;
    bf16* kh = qkv + 2097152;
    bf16* vh = qkv + 4194304;

    k_bar_init<<<1, 64, 0, stream>>>(bar, gen);

    // weff_z = zw @ Wz^T
    P3 pw;
    pw.a[0] = qw;  pw.a[1] = kw;  pw.a[2] = vw;
    pw.b[0] = ipw; pw.b[1] = ipw + 262144; pw.b[2] = ipw + 524288;
    pw.bi[0] = pw.bi[1] = pw.bi[2] = nullptr;
    pw.c[0] = weff; pw.c[1] = weff + 393216; pw.c[2] = weff + 786432;
    mgemm<float, float, bf16, true, false><<<dim3(12, 8, 3), 256, 0, stream>>>(pw, 768, 512, 512);

    // qkv_z = emb @ weff_z + bias_z
    P3 pq;
    pq.a[0] = pq.a[1] = pq.a[2] = emb;
    pq.b[0] = weff; pq.b[1] = weff + 393216; pq.b[2] = weff + 786432;
    pq.bi[0] = ipb; pq.bi[1] = ipb + 512; pq.bi[2] = ipb + 1024;
    pq.c[0] = qh; pq.c[1] = kh; pq.c[2] = vh;
    mgemm<float, bf16, bf16, false, true><<<dim3(64, 8, 3), 256, 0, stream>>>(pq, 4096, 512, 768);

    attn_mfma<<<dim3(512), 256, 0, stream>>>(qh, kh, vh, oatt);

    // X = oatt @ out_w^T + out_b
    P3 pt;
    pt.a[0] = oatt; pt.b[0] = ow; pt.bi[0] = ob; pt.c[0] = X;
    pt.a[1] = pt.a[2] = pt.b[1] = pt.b[2] = nullptr;
    pt.bi[1] = pt.bi[2] = nullptr; pt.c[1] = pt.c[2] = nullptr;
    mgemm<bf16, float, float, true, true><<<dim3(64, 8, 1), 256, 0, stream>>>(pt, 4096, 512, 512);

    dkm_persist<<<dim3(128), 512, 0, stream>>>(X, idx, Cacc, Cb0, Cb1,
                                               asumb, diffb, cnormb, bar, gen, out);
}